// Round 6
// baseline (3041.908 us; speedup 1.0000x reference)
//
#include <hip/hip_runtime.h>
#include <hip/hip_bf16.h>

// Problem constants
#define B_    128
#define T_    512
#define IN_   128
#define H_    1024
#define OUT_  64
#define KTOT  1152          // IN_ + H_
#define GH    64            // hidden groups (16 units, 64 gate cols each)
#define GB    4             // batch groups (32 rows each)
// Blocked Hall layout: [t][gh(64)][b(128)][16] ushort.
// t-slab stride = 131072 ushorts (256KB); gh block = 2048 ushorts (4KB).
#define HSLAB 131072
#define HBLK  2048

typedef short bf16x8 __attribute__((ext_vector_type(8)));
typedef float f32x4  __attribute__((ext_vector_type(4)));

#define MFMA(a,b,c) __builtin_amdgcn_mfma_f32_16x16x32_bf16((a),(b),(c),0,0,0)

__device__ __forceinline__ unsigned short f2bf(float x) {
    unsigned int xi = __float_as_uint(x);
    unsigned int r  = (xi + 0x7fffu + ((xi >> 16) & 1u)) >> 16;
    return (unsigned short)r;
}

// ---------------------------------------------------------------------------
// Pack combined recurrent weights: Wp[c][k] bf16, c = gh*64 + unit_local*4 + gate
// gate 0,1,2 = f,i,z (kernel_fiz col gate*H + j); gate 3 = r (kernel_r col j)
// ---------------------------------------------------------------------------
__global__ void pack_weights(const float* __restrict__ kfiz, const float* __restrict__ kr,
                             const float* __restrict__ bfiz, const float* __restrict__ br,
                             unsigned short* __restrict__ Wp, float* __restrict__ biasp)
{
    const int c    = blockIdx.x;            // 0..4095
    const int gh   = c >> 6, nl = c & 63;
    const int j    = gh * 16 + (nl >> 2);
    const int gate = nl & 3;
    for (int k = threadIdx.x; k < KTOT; k += 256) {
        float v = (gate < 3) ? kfiz[(size_t)k * 3072 + gate * 1024 + j]
                             : kr[(size_t)k * 1024 + j];
        Wp[(size_t)c * KTOT + k] = f2bf(v);
    }
    if (threadIdx.x == 0)
        biasp[c] = (gate < 3) ? bfiz[gate * 1024 + j] : br[j];
}

// u (B,T,IN) fp32 -> Ubf (T,B,IN) bf16
__global__ void pack_u(const float* __restrict__ u, unsigned short* __restrict__ Ubf)
{
    size_t i = (size_t)blockIdx.x * 256 + threadIdx.x;   // < 8388608
    int t = (int)(i >> 14);
    int rem = (int)(i & 16383);
    int b = rem >> 7, k = rem & 127;
    Ubf[i] = f2bf(u[((size_t)b << 16) + ((size_t)t << 7) + k]);
}

// W_out (H,OUT) fp32 -> Wob[o][k] bf16
__global__ void pack_wout(const float* __restrict__ wo, unsigned short* __restrict__ Wob)
{
    const int o = blockIdx.x;               // 0..63
    for (int k = threadIdx.x; k < H_; k += 256)
        Wob[(size_t)o * H_ + k] = f2bf(wo[(size_t)k * OUT_ + o]);
}

// ---------------------------------------------------------------------------
// Persistent recurrent scan — round-4 proven core (1900us) + per-wave SUBSET
// flag polling (B1 deleted).
//  * Producer (unchanged): wave0 funnel publishes the WG's 1KB contiguous
//    patch (2x 512B stores, full lines), waitcnt(0) drain, THEN flag — flag
//    means "globally visible", which is what keeps consumer loads PLAIN.
//  * Consumer loads (unchanged): plain cached loads; 32 WGs/XCD share one
//    L2-resident copy of the per-step h-panel (round-2/5 lesson: agent-scope
//    data loads forfeit this 32x amortization and stall on LLC latency).
//  * NEW: wave (*,nj) polls only its own 18 producers' flags (10 for nj=0)
//    — cols [18nj-8, 18nj+10) — and proceeds as soon as THEY are visible.
//    Coupling per step drops from max-of-64 (B1) to max-of-18; wave0's
//    publish drain overlaps other waves' polls instead of gating them at B1.
//    asm memory barrier after the poll keeps plain h-loads from hoisting;
//    loop-exit data-dependence on the flag value orders issue in HW.
//  * Liveness: producers set every (t,gb,gh) flag unconditionally each step
//    (same protocol as the proven run) -> unbounded poll is safe.
// ---------------------------------------------------------------------------
__global__ void __launch_bounds__(512, 2)
lstm_scan(const float* __restrict__ x0,
          const unsigned short* __restrict__ Wp,
          const float* __restrict__ biasp,
          const unsigned short* __restrict__ Ubf,
          unsigned short* __restrict__ Hall,
          int* __restrict__ Flag)
{
    __shared__ float part[4 * 8 * 320];       // [nj][mi*4+tl][col*20 + row] 40 KB
    __shared__ unsigned short hT[32 * 16];    // 1 KB h-tile for coalesced publish

    const int tid  = threadIdx.x;
    const int bid  = blockIdx.x;
    const int gb   = (bid & 7) >> 1;                 // XCD-pair -> one gb group
    const int gh   = ((bid & 1) << 5) | (bid >> 3);  // 0..63, unique per gb
    const int wave = tid >> 6;
    const int lane = tid & 63;
    const int mi   = wave & 1;
    const int nj   = wave >> 1;               // K-slice AND owner-tile index, 0..3
    const int quad = lane >> 4;
    const int l15  = lane & 15;
    const int g    = l15 & 3;                 // gate id of this lane's column

    // Weights: tile tl cols gh*64+tl*16+l15, K-slice nj chunks kk (9 x 32).
    f32x4 wregf[36];
    #pragma unroll
    for (int tl = 0; tl < 4; ++tl)
        #pragma unroll
        for (int kk = 0; kk < 9; ++kk)
            wregf[tl * 9 + kk] = *reinterpret_cast<const f32x4*>(
                Wp + (size_t)(gh * 64 + tl * 16 + l15) * KTOT + nj * 288 + kk * 32 + quad * 8);
    #pragma unroll
    for (int i = 0; i < 36; ++i)
        asm volatile("" : "+v"(wregf[i]));    // pin: no remat, keep in VGPRs

    const float bias = biasp[gh * 64 + nj * 16 + l15];   // owner-role bias

    const int rowBase = gb * 32 + mi * 16;
    const int j       = gh * 16 + nj * 4 + (l15 >> 2);   // owner-role unit col

    // c-state (fp32, replicated across the 4 gate lanes of each unit)
    float cst[4];
    #pragma unroll
    for (int r = 0; r < 4; ++r)
        cst[r] = x0[(size_t)(rowBase + quad * 4 + r) * 2048 + 1024 + j];

    // h0 -> Hall[0] (blocked layout; WG's 1KB patch, contiguous full lines)
    {
        int m = tid >> 4, uu = tid & 15;      // 512 threads, 512 elems
        int b = gb * 32 + m;
        unsigned short hv = f2bf(x0[(size_t)b * 2048 + gh * 16 + uu]);
        __hip_atomic_store(&Hall[(size_t)gh * HBLK + (size_t)b * 16 + uu], hv,
                           __ATOMIC_RELAXED, __HIP_MEMORY_SCOPE_AGENT);
    }
    __syncthreads();                           // one-time drain (off steady path)
    if (tid == 0)
        __hip_atomic_store(&Flag[(size_t)gb * 64 + gh], 1,
                           __ATOMIC_RELAXED, __HIP_MEMORY_SCOPE_AGENT);

    const int aRow = rowBase + l15;            // A-frag row (batch index)
    const unsigned short* aU = Ubf + (size_t)aRow * IN_ + quad * 8;
    // Blocked consumer base: chunk kk (col c = nj*288-128+kk*32) lives in
    // block (nj*18-8+2*kk)+(quad>>1), byte-col (quad&1)*8 ushorts.
    const unsigned short* aH = Hall + (size_t)aRow * 16 + (quad >> 1) * HBLK + (quad & 1) * 8;
    const ptrdiff_t hBlk0 = (ptrdiff_t)(nj * 18 - 8) * HBLK;   // kk=0 block offset

    const int kk0 = (nj == 0) ? 4 : 0;         // post-poll chunk start

    // Subset-poll lane mapping: wave (*,nj) depends on producer cols
    // [nj*288-128, nj*288+160) -> gh' in [18nj-8, 18nj+10)  (nj=0: [0,10)).
    const int fBase = (nj == 0) ? 0 : (nj * 18 - 8);
    const int fCnt  = (nj == 0) ? 10 : 18;
    const int fl    = fBase + ((lane < fCnt) ? lane : (fCnt - 1));

    for (int t = 0; t < T_; ++t) {
        f32x4 acc[4] = {{0.f,0.f,0.f,0.f},{0.f,0.f,0.f,0.f},
                        {0.f,0.f,0.f,0.f},{0.f,0.f,0.f,0.f}};

        // ---- pre-poll u-part (nj==0 waves own K-chunks 0..3 = u) ----
        if (nj == 0) {
            const unsigned short* au = aU + (size_t)t * (B_ * IN_);
            #pragma unroll
            for (int kk = 0; kk < 4; ++kk) {
                bf16x8 av = *reinterpret_cast<const bf16x8*>(au + kk * 32);
                #pragma unroll
                for (int tl = 0; tl < 4; ++tl)
                    acc[tl] = MFMA(av, __builtin_bit_cast(bf16x8, wregf[tl * 9 + kk]), acc[tl]);
            }
        }

        // ---- per-wave subset flag poll (flag = "visible"; no WG barrier) ----
        {
            const int* fp = Flag + ((size_t)t * GB + gb) * 64 + fl;
            int v = __hip_atomic_load(fp, __ATOMIC_RELAXED, __HIP_MEMORY_SCOPE_AGENT);
            while (!__all(v != 0))
                v = __hip_atomic_load(fp, __ATOMIC_RELAXED, __HIP_MEMORY_SCOPE_AGENT);
        }
        asm volatile("" ::: "memory");         // no plain h-load hoists above poll

        // ---- h-part: this wave's K-slice (blocked layout, plain 512B runs) ----
        const ptrdiff_t hoff = (ptrdiff_t)t * HSLAB + hBlk0;
        bf16x8 a[9];
        #pragma unroll
        for (int kk = 0; kk < 9; ++kk)
            if (kk >= kk0)
                a[kk] = *reinterpret_cast<const bf16x8*>(aH + hoff + (ptrdiff_t)kk * (2 * HBLK));
        #pragma unroll
        for (int kk = 0; kk < 9; ++kk)
            if (kk >= kk0) {
                #pragma unroll
                for (int tl = 0; tl < 4; ++tl)
                    acc[tl] = MFMA(a[kk], __builtin_bit_cast(bf16x8, wregf[tl * 9 + kk]), acc[tl]);
            }

        // ---- write partials to LDS: part[nj][mi*4+tl][col l15][rows quad*4..] ----
        #pragma unroll
        for (int tl = 0; tl < 4; ++tl)
            *reinterpret_cast<f32x4*>(
                &part[(nj * 8 + mi * 4 + tl) * 320 + l15 * 20 + quad * 4]) = acc[tl];
        __syncthreads();                       // B2a

        // ---- owner reduce (this wave owns tile tl == nj for row-half mi) ----
        f32x4 s = {bias, bias, bias, bias};
        {
            const int rbase = (mi * 4 + nj) * 320 + l15 * 20 + quad * 4;
            #pragma unroll
            for (int njj = 0; njj < 4; ++njj)
                s += *reinterpret_cast<const f32x4*>(&part[njj * 2560 + rbase]);
        }

        // ---- epilogue: activations, cross-gate exchange, state update ----
        #pragma unroll
        for (int r = 0; r < 4; ++r) {
            float pre = s[r];
            float sg  = 1.0f / (1.0f + __expf((g == 3) ? -2.0f * pre : -pre));
            float act = (g == 3) ? 2.0f * sg - 1.0f : sg;
            float x1 = __shfl_xor(act, 1);
            float x2 = __shfl_xor(act, 2);
            float x3 = __shfl_xor(x1, 2);
            float fv = (g == 0) ? act : (g == 1) ? x1 : (g == 2) ? x2 : x3;
            int gi = g ^ 1;
            float iv = (gi == 0) ? act : (gi == 1) ? x1 : (gi == 2) ? x2 : x3;
            int gz = g ^ 2;
            float zv = (gz == 0) ? act : (gz == 1) ? x1 : (gz == 2) ? x2 : x3;
            int gr = g ^ 3;
            float rv = (gr == 0) ? act : (gr == 1) ? x1 : (gr == 2) ? x2 : x3;

            float cn = fv * cst[r] + iv * rv;
            cst[r] = cn;
            float th = 2.0f / (1.0f + __expf(-2.0f * cn)) - 1.0f;
            float hn = zv * th;
            if (g == 0)
                hT[(mi * 16 + quad * 4 + r) * 16 + nj * 4 + (l15 >> 2)] = f2bf(hn);
        }

        __syncthreads();                       // B2b: hT complete

        // ---- wave0: publish the WG's 1KB CONTIGUOUS patch, drain, flag ----
        if (wave == 0) {
            const unsigned long long* lp =
                reinterpret_cast<const unsigned long long*>(hT);
            unsigned long long lo = lp[lane], hi = lp[lane + 64];
            size_t base = (size_t)(t + 1) * HSLAB + (size_t)gh * HBLK
                        + (size_t)(gb * 32) * 16;
            __hip_atomic_store((unsigned long long*)&Hall[base + lane * 4],       lo,
                               __ATOMIC_RELAXED, __HIP_MEMORY_SCOPE_AGENT);
            __hip_atomic_store((unsigned long long*)&Hall[base + 256 + lane * 4], hi,
                               __ATOMIC_RELAXED, __HIP_MEMORY_SCOPE_AGENT);
            __builtin_amdgcn_s_waitcnt(0);     // drain: flag must mean "visible"
            asm volatile("" ::: "memory");
            if (lane == 0)
                __hip_atomic_store(&Flag[((size_t)(t + 1) * GB + gb) * 64 + gh], 1,
                                   __ATOMIC_RELAXED, __HIP_MEMORY_SCOPE_AGENT);
        }
    }
}

// ---------------------------------------------------------------------------
// y[b][t][o] = Hall[t+1][.][b][.] @ Wob[o][:] + bout[o]   (blocked Hall)
// ---------------------------------------------------------------------------
__global__ void __launch_bounds__(256, 2)
out_gemm(const unsigned short* __restrict__ Hall,
         const unsigned short* __restrict__ Wob,
         const float* __restrict__ bout,
         float* __restrict__ y)
{
    const int tid  = threadIdx.x, wave = tid >> 6, lane = tid & 63;
    const int quad = lane >> 4, l15 = lane & 15;
    const int R    = blockIdx.x * 64 + wave * 16;      // flat row t*128+b

    f32x4 acc[4];
    #pragma unroll
    for (int nt = 0; nt < 4; ++nt) {
        float bb = bout[nt * 16 + l15];
        acc[nt] = {bb, bb, bb, bb};
    }
    const int fr = R + l15;                    // flat row; same t across the wave
    const unsigned short* ap = Hall + ((size_t)(fr >> 7) + 1) * HSLAB
                             + (size_t)(fr & 127) * 16
                             + (quad >> 1) * HBLK + (quad & 1) * 8;
    #pragma unroll 4
    for (int kk = 0; kk < 32; ++kk) {          // k-chunk kk covers blocks 2kk,2kk+1
        bf16x8 av = *reinterpret_cast<const bf16x8*>(ap + (size_t)kk * (2 * HBLK));
        #pragma unroll
        for (int nt = 0; nt < 4; ++nt) {
            bf16x8 bv = *reinterpret_cast<const bf16x8*>(
                Wob + (size_t)(nt * 16 + l15) * H_ + kk * 32 + quad * 8);
            acc[nt] = MFMA(av, bv, acc[nt]);
        }
    }
    #pragma unroll
    for (int nt = 0; nt < 4; ++nt)
        #pragma unroll
        for (int r = 0; r < 4; ++r) {
            int row = R + quad * 4 + r;
            int b = row & 127, t = row >> 7;
            y[((size_t)b << 15) + ((size_t)t << 6) + nt * 16 + l15] = acc[nt][r];
        }
}

// ---------------------------------------------------------------------------
extern "C" void kernel_launch(void* const* d_in, const int* in_sizes, int n_in,
                              void* d_out, int out_size, void* d_ws, size_t ws_size,
                              hipStream_t stream)
{
    const float* u    = (const float*)d_in[0];
    const float* x0   = (const float*)d_in[1];
    const float* kfiz = (const float*)d_in[2];
    const float* bfiz = (const float*)d_in[3];
    const float* kr   = (const float*)d_in[4];
    const float* br   = (const float*)d_in[5];
    const float* wo   = (const float*)d_in[6];
    const float* bo   = (const float*)d_in[7];
    float* y = (float*)d_out;

    char* ws = (char*)d_ws;
    size_t off = 0;
    unsigned short* Wp    = (unsigned short*)(ws + off); off += (size_t)4096 * KTOT * 2;        // 9,437,184
    float*          biasp = (float*)(ws + off);          off += (size_t)4096 * 4;               // 16,384
    unsigned short* Wob   = (unsigned short*)(ws + off); off += (size_t)OUT_ * H_ * 2;          // 131,072
    unsigned short* Ubf   = (unsigned short*)(ws + off); off += (size_t)T_ * B_ * IN_ * 2;      // 16,777,216
    unsigned short* Hall  = (unsigned short*)(ws + off); off += (size_t)(T_ + 1) * B_ * H_ * 2; // 134,479,872
    int*            Flag  = (int*)(ws + off);            off += (size_t)(T_ + 1) * GB * 64 * 4; // 525,312
    if (off > ws_size) return;   // workspace too small: deterministic visible failure

    hipMemsetAsync(Flag, 0, (size_t)(T_ + 1) * GB * 64 * 4, stream);
    hipLaunchKernelGGL(pack_weights, dim3(4096),  dim3(256), 0, stream, kfiz, kr, bfiz, br, Wp, biasp);
    hipLaunchKernelGGL(pack_u,       dim3(32768), dim3(256), 0, stream, u, Ubf);
    hipLaunchKernelGGL(pack_wout,    dim3(64),    dim3(256), 0, stream, wo, Wob);

    void* args[] = { (void*)&x0, (void*)&Wp, (void*)&biasp, (void*)&Ubf, (void*)&Hall, (void*)&Flag };
    hipLaunchCooperativeKernel((void*)lstm_scan, dim3(GB * GH), dim3(512), args, 0, stream);

    hipLaunchKernelGGL(out_gemm, dim3((T_ * B_) / 64), dim3(256), 0, stream, Hall, Wob, bo, y);
}

// Round 8
// 2920.993 us; speedup vs baseline: 1.0414x; 1.0414x over previous
//
#include <hip/hip_runtime.h>
#include <hip/hip_bf16.h>

// Problem constants
#define B_    128
#define T_    512
#define IN_   128
#define H_    1024
#define OUT_  64
#define KTOT  1152          // IN_ + H_
#define GH    64            // hidden groups (16 units, 64 gate cols each)
#define GB    4             // batch groups (32 rows each)
// Blocked Hall layout: [t][gh(64)][b(128)][16] ushort.
// t-slab stride = 131072 ushorts (256KB); gh block = 2048 ushorts (4KB).
#define HSLAB 131072
#define HBLK  2048

typedef short bf16x8 __attribute__((ext_vector_type(8)));
typedef float f32x4  __attribute__((ext_vector_type(4)));
typedef unsigned int   u32x4 __attribute__((ext_vector_type(4)));
typedef unsigned short u16x2 __attribute__((ext_vector_type(2)));

#define MFMA(a,b,c) __builtin_amdgcn_mfma_f32_16x16x32_bf16((a),(b),(c),0,0,0)

__device__ __forceinline__ unsigned short f2bf(float x) {
    unsigned int xi = __float_as_uint(x);
    unsigned int r  = (xi + 0x7fffu + ((xi >> 16) & 1u)) >> 16;
    return (unsigned short)r;
}

// ---------------------------------------------------------------------------
// Pack combined recurrent weights: Wp[c][k] bf16, c = gh*64 + unit_local*4 + gate
// gate 0,1,2 = f,i,z (kernel_fiz col gate*H + j); gate 3 = r (kernel_r col j)
// ---------------------------------------------------------------------------
__global__ void pack_weights(const float* __restrict__ kfiz, const float* __restrict__ kr,
                             const float* __restrict__ bfiz, const float* __restrict__ br,
                             unsigned short* __restrict__ Wp, float* __restrict__ biasp)
{
    const int c    = blockIdx.x;            // 0..4095
    const int gh   = c >> 6, nl = c & 63;
    const int j    = gh * 16 + (nl >> 2);
    const int gate = nl & 3;
    for (int k = threadIdx.x; k < KTOT; k += 256) {
        float v = (gate < 3) ? kfiz[(size_t)k * 3072 + gate * 1024 + j]
                             : kr[(size_t)k * 1024 + j];
        Wp[(size_t)c * KTOT + k] = f2bf(v);
    }
    if (threadIdx.x == 0)
        biasp[c] = (gate < 3) ? bfiz[gate * 1024 + j] : br[j];
}

// u (B,T,IN) fp32 -> Ubf (T,B,IN) bf16
__global__ void pack_u(const float* __restrict__ u, unsigned short* __restrict__ Ubf)
{
    size_t i = (size_t)blockIdx.x * 256 + threadIdx.x;   // < 8388608
    int t = (int)(i >> 14);
    int rem = (int)(i & 16383);
    int b = rem >> 7, k = rem & 127;
    Ubf[i] = f2bf(u[((size_t)b << 16) + ((size_t)t << 7) + k]);
}

// W_out (H,OUT) fp32 -> Wob[o][k] bf16
__global__ void pack_wout(const float* __restrict__ wo, unsigned short* __restrict__ Wob)
{
    const int o = blockIdx.x;               // 0..63
    for (int k = threadIdx.x; k < H_; k += 256)
        Wob[(size_t)o * H_ + k] = f2bf(wo[(size_t)k * OUT_ + o]);
}

// ---------------------------------------------------------------------------
// Persistent recurrent scan — round-4 proven core with the producer DRAIN
// REMOVED (flag = "issued"), guarded by a sentinel safety net. HANG-PROOF:
// every loop in this kernel is bounded; any protocol failure degrades to a
// visible absmax failure in bounded time, never a GPU hang.
//  * Producer: wave0 funnel publishes the WG's 1KB contiguous patch (2x 512B
//    full-line stores) and the flag back-to-back, NO vmcnt drain — data and
//    flag fly to the LLC concurrently; the store-ack RTT leaves the chain.
//  * Consumer (steady state = round 4): ONE polling wave per WG (round-6
//    lesson: more pollers congest the LLC flag lines), B1, then PLAIN cached
//    h-loads — 32 WGs/XCD share one L2 copy (round-2/5 lesson: agent-scope
//    bulk loads forfeit this and stall on LLC latency).
//  * Safety net: Hall pre-memset to 0xFFFF (bf16 -NaN; |h|<1 so f2bf can
//    never produce it). After the plain loads, a ~20-VALU in-register max
//    check validates all granules; since the flag was issued AFTER the data,
//    a poll RTT later the data has nearly always landed -> check passes.
//    Rare straggler (flag beat data, or a first-touch cached a pre-arrival
//    line making that L2 line stale for plain loads): bounded AGENT-scope
//    reload loop (bypasses the stale L2 copy) + s_sleep backoff; 8B
//    single-writer granules make tearing impossible.
// ---------------------------------------------------------------------------
__global__ void __launch_bounds__(512, 2)
lstm_scan(const float* __restrict__ x0,
          const unsigned short* __restrict__ Wp,
          const float* __restrict__ biasp,
          const unsigned short* __restrict__ Ubf,
          unsigned short* __restrict__ Hall,
          int* __restrict__ Flag)
{
    __shared__ float part[4 * 8 * 320];       // [nj][mi*4+tl][col*20 + row] 40 KB
    __shared__ unsigned short hT[32 * 16];    // 1 KB h-tile for coalesced publish

    const int tid  = threadIdx.x;
    const int bid  = blockIdx.x;
    const int gb   = (bid & 7) >> 1;                 // XCD-pair -> one gb group
    const int gh   = ((bid & 1) << 5) | (bid >> 3);  // 0..63, unique per gb
    const int wave = tid >> 6;
    const int lane = tid & 63;
    const int mi   = wave & 1;
    const int nj   = wave >> 1;               // K-slice AND owner-tile index, 0..3
    const int quad = lane >> 4;
    const int l15  = lane & 15;
    const int g    = l15 & 3;                 // gate id of this lane's column

    // Weights: tile tl cols gh*64+tl*16+l15, K-slice nj chunks kk (9 x 32).
    f32x4 wregf[36];
    #pragma unroll
    for (int tl = 0; tl < 4; ++tl)
        #pragma unroll
        for (int kk = 0; kk < 9; ++kk)
            wregf[tl * 9 + kk] = *reinterpret_cast<const f32x4*>(
                Wp + (size_t)(gh * 64 + tl * 16 + l15) * KTOT + nj * 288 + kk * 32 + quad * 8);
    #pragma unroll
    for (int i = 0; i < 36; ++i)
        asm volatile("" : "+v"(wregf[i]));    // pin: no remat, keep in VGPRs

    const float bias = biasp[gh * 64 + nj * 16 + l15];   // owner-role bias

    const int rowBase = gb * 32 + mi * 16;
    const int j       = gh * 16 + nj * 4 + (l15 >> 2);   // owner-role unit col

    // c-state (fp32, replicated across the 4 gate lanes of each unit)
    float cst[4];
    #pragma unroll
    for (int r = 0; r < 4; ++r)
        cst[r] = x0[(size_t)(rowBase + quad * 4 + r) * 2048 + 1024 + j];

    // h0 -> Hall[0] (blocked layout; WG's 1KB patch, contiguous full lines)
    {
        int m = tid >> 4, uu = tid & 15;      // 512 threads, 512 elems
        int b = gb * 32 + m;
        unsigned short hv = f2bf(x0[(size_t)b * 2048 + gh * 16 + uu]);
        __hip_atomic_store(&Hall[(size_t)gh * HBLK + (size_t)b * 16 + uu], hv,
                           __ATOMIC_RELAXED, __HIP_MEMORY_SCOPE_AGENT);
    }
    __syncthreads();                           // one-time drain (off steady path)
    if (tid == 0)
        __hip_atomic_store(&Flag[(size_t)gb * 64 + gh], 1,
                           __ATOMIC_RELAXED, __HIP_MEMORY_SCOPE_AGENT);

    const int aRow = rowBase + l15;            // A-frag row (batch index)
    const unsigned short* aU = Ubf + (size_t)aRow * IN_ + quad * 8;
    // Blocked consumer base: chunk kk (col c = nj*288-128+kk*32) lives in
    // block (nj*18-8+2*kk)+(quad>>1), byte-col (quad&1)*8 ushorts.
    const unsigned short* aH = Hall + (size_t)aRow * 16 + (quad >> 1) * HBLK + (quad & 1) * 8;
    const ptrdiff_t hBlk0 = (ptrdiff_t)(nj * 18 - 8) * HBLK;   // kk=0 block offset

    const int kk0 = (nj == 0) ? 4 : 0;         // post-poll chunk start

    for (int t = 0; t < T_; ++t) {
        f32x4 acc[4] = {{0.f,0.f,0.f,0.f},{0.f,0.f,0.f,0.f},
                        {0.f,0.f,0.f,0.f},{0.f,0.f,0.f,0.f}};

        // ---- pre-poll u-part (nj==0 waves own K-chunks 0..3 = u) ----
        if (nj == 0) {
            const unsigned short* au = aU + (size_t)t * (B_ * IN_);
            #pragma unroll
            for (int kk = 0; kk < 4; ++kk) {
                bf16x8 av = *reinterpret_cast<const bf16x8*>(au + kk * 32);
                #pragma unroll
                for (int tl = 0; tl < 4; ++tl)
                    acc[tl] = MFMA(av, __builtin_bit_cast(bf16x8, wregf[tl * 9 + kk]), acc[tl]);
            }
        }

        // ---- wait for h[t]: wave0-only 64-flag poll (BOUNDED: hang-proof) ----
        if (wave == 0) {
            const int* fp = Flag + ((size_t)t * GB + gb) * 64 + lane;
            int v = __hip_atomic_load(fp, __ATOMIC_RELAXED, __HIP_MEMORY_SCOPE_AGENT);
            for (int guard = 0; guard < 16384 && !__all(v != 0); ++guard)
                v = __hip_atomic_load(fp, __ATOMIC_RELAXED, __HIP_MEMORY_SCOPE_AGENT);
            // on guard expiry: proceed; sentinel net below catches bad data.
        }
        __syncthreads();                       // B1

        // ---- h-part fast path: plain cached loads (L2-amortized) ----
        const ptrdiff_t hoff = (ptrdiff_t)t * HSLAB + hBlk0;
        bf16x8 a[9];
        #pragma unroll
        for (int kk = 0; kk < 9; ++kk)
            if (kk >= kk0)
                a[kk] = *reinterpret_cast<const bf16x8*>(aH + hoff + (ptrdiff_t)kk * (2 * HBLK));

        // ---- sentinel validation (~20 VALU; passes in steady state) ----
        {
            u16x2 mx = (u16x2){0, 0};
            #pragma unroll
            for (int kk = 0; kk < 9; ++kk)
                if (kk >= kk0) {
                    u32x4 w = __builtin_bit_cast(u32x4, a[kk]);
                    #pragma unroll
                    for (int e = 0; e < 4; ++e)
                        mx = __builtin_elementwise_max(mx, __builtin_bit_cast(u16x2, w[e]));
                }
            bool ok = (mx.x != 0xFFFFu) && (mx.y != 0xFFFFu);
            if (!__all(ok)) {
                // Straggler / stale-L2-line fallback: AGENT loads bypass the
                // poisoned L2 copy; bounded spin -> visible failure, no hang.
                for (int spin = 0; spin < 8192; ++spin) {
                    union AU { unsigned long long q[2]; bf16x8 v; } tmp;
                    u16x2 m2 = (u16x2){0, 0};
                    #pragma unroll
                    for (int kk = 0; kk < 9; ++kk)
                        if (kk >= kk0) {
                            const unsigned long long* gp =
                                reinterpret_cast<const unsigned long long*>(
                                    aH + hoff + (ptrdiff_t)kk * (2 * HBLK));
                            tmp.q[0] = __hip_atomic_load(gp,     __ATOMIC_RELAXED, __HIP_MEMORY_SCOPE_AGENT);
                            tmp.q[1] = __hip_atomic_load(gp + 1, __ATOMIC_RELAXED, __HIP_MEMORY_SCOPE_AGENT);
                            a[kk] = tmp.v;
                            u32x4 w = __builtin_bit_cast(u32x4, tmp.v);
                            #pragma unroll
                            for (int e = 0; e < 4; ++e)
                                m2 = __builtin_elementwise_max(m2, __builtin_bit_cast(u16x2, w[e]));
                        }
                    bool ok2 = (m2.x != 0xFFFFu) && (m2.y != 0xFFFFu);
                    if (__all(ok2)) break;
                    __builtin_amdgcn_s_sleep(1);
                }
            }
        }

        // ---- h-part MFMAs ----
        #pragma unroll
        for (int kk = 0; kk < 9; ++kk)
            if (kk >= kk0) {
                #pragma unroll
                for (int tl = 0; tl < 4; ++tl)
                    acc[tl] = MFMA(a[kk], __builtin_bit_cast(bf16x8, wregf[tl * 9 + kk]), acc[tl]);
            }

        // ---- write partials to LDS: part[nj][mi*4+tl][col l15][rows quad*4..] ----
        #pragma unroll
        for (int tl = 0; tl < 4; ++tl)
            *reinterpret_cast<f32x4*>(
                &part[(nj * 8 + mi * 4 + tl) * 320 + l15 * 20 + quad * 4]) = acc[tl];
        __syncthreads();                       // B2a

        // ---- owner reduce (this wave owns tile tl == nj for row-half mi) ----
        f32x4 s = {bias, bias, bias, bias};
        {
            const int rbase = (mi * 4 + nj) * 320 + l15 * 20 + quad * 4;
            #pragma unroll
            for (int njj = 0; njj < 4; ++njj)
                s += *reinterpret_cast<const f32x4*>(&part[njj * 2560 + rbase]);
        }

        // ---- epilogue: activations, cross-gate exchange, state update ----
        #pragma unroll
        for (int r = 0; r < 4; ++r) {
            float pre = s[r];
            float sg  = 1.0f / (1.0f + __expf((g == 3) ? -2.0f * pre : -pre));
            float act = (g == 3) ? 2.0f * sg - 1.0f : sg;
            float x1 = __shfl_xor(act, 1);
            float x2 = __shfl_xor(act, 2);
            float x3 = __shfl_xor(x1, 2);
            float fv = (g == 0) ? act : (g == 1) ? x1 : (g == 2) ? x2 : x3;
            int gi = g ^ 1;
            float iv = (gi == 0) ? act : (gi == 1) ? x1 : (gi == 2) ? x2 : x3;
            int gz = g ^ 2;
            float zv = (gz == 0) ? act : (gz == 1) ? x1 : (gz == 2) ? x2 : x3;
            int gr = g ^ 3;
            float rv = (gr == 0) ? act : (gr == 1) ? x1 : (gr == 2) ? x2 : x3;

            float cn = fv * cst[r] + iv * rv;
            cst[r] = cn;
            float th = 2.0f / (1.0f + __expf(-2.0f * cn)) - 1.0f;
            float hn = zv * th;
            if (g == 0)
                hT[(mi * 16 + quad * 4 + r) * 16 + nj * 4 + (l15 >> 2)] = f2bf(hn);
        }

        __syncthreads();                       // B2b: hT complete

        // ---- wave0: publish 1KB patch + flag, NO drain (fire-and-forget) ----
        if (wave == 0) {
            const unsigned long long* lp =
                reinterpret_cast<const unsigned long long*>(hT);
            unsigned long long lo = lp[lane], hi = lp[lane + 64];
            size_t base = (size_t)(t + 1) * HSLAB + (size_t)gh * HBLK
                        + (size_t)(gb * 32) * 16;
            __hip_atomic_store((unsigned long long*)&Hall[base + lane * 4],       lo,
                               __ATOMIC_RELAXED, __HIP_MEMORY_SCOPE_AGENT);
            __hip_atomic_store((unsigned long long*)&Hall[base + 256 + lane * 4], hi,
                               __ATOMIC_RELAXED, __HIP_MEMORY_SCOPE_AGENT);
            asm volatile("" ::: "memory");     // keep issue order: data -> flag
            if (lane == 0)
                __hip_atomic_store(&Flag[((size_t)(t + 1) * GB + gb) * 64 + gh], 1,
                                   __ATOMIC_RELAXED, __HIP_MEMORY_SCOPE_AGENT);
        }
    }
}

// ---------------------------------------------------------------------------
// y[b][t][o] = Hall[t+1][.][b][.] @ Wob[o][:] + bout[o]   (blocked Hall)
// ---------------------------------------------------------------------------
__global__ void __launch_bounds__(256, 2)
out_gemm(const unsigned short* __restrict__ Hall,
         const unsigned short* __restrict__ Wob,
         const float* __restrict__ bout,
         float* __restrict__ y)
{
    const int tid  = threadIdx.x, wave = tid >> 6, lane = tid & 63;
    const int quad = lane >> 4, l15 = lane & 15;
    const int R    = blockIdx.x * 64 + wave * 16;      // flat row t*128+b

    f32x4 acc[4];
    #pragma unroll
    for (int nt = 0; nt < 4; ++nt) {
        float bb = bout[nt * 16 + l15];
        acc[nt] = {bb, bb, bb, bb};
    }
    const int fr = R + l15;                    // flat row; same t across the wave
    const unsigned short* ap = Hall + ((size_t)(fr >> 7) + 1) * HSLAB
                             + (size_t)(fr & 127) * 16
                             + (quad >> 1) * HBLK + (quad & 1) * 8;
    #pragma unroll 4
    for (int kk = 0; kk < 32; ++kk) {          // k-chunk kk covers blocks 2kk,2kk+1
        bf16x8 av = *reinterpret_cast<const bf16x8*>(ap + (size_t)kk * (2 * HBLK));
        #pragma unroll
        for (int nt = 0; nt < 4; ++nt) {
            bf16x8 bv = *reinterpret_cast<const bf16x8*>(
                Wob + (size_t)(nt * 16 + l15) * H_ + kk * 32 + quad * 8);
            acc[nt] = MFMA(av, bv, acc[nt]);
        }
    }
    #pragma unroll
    for (int nt = 0; nt < 4; ++nt)
        #pragma unroll
        for (int r = 0; r < 4; ++r) {
            int row = R + quad * 4 + r;
            int b = row & 127, t = row >> 7;
            y[((size_t)b << 15) + ((size_t)t << 6) + nt * 16 + l15] = acc[nt][r];
        }
}

// ---------------------------------------------------------------------------
extern "C" void kernel_launch(void* const* d_in, const int* in_sizes, int n_in,
                              void* d_out, int out_size, void* d_ws, size_t ws_size,
                              hipStream_t stream)
{
    const float* u    = (const float*)d_in[0];
    const float* x0   = (const float*)d_in[1];
    const float* kfiz = (const float*)d_in[2];
    const float* bfiz = (const float*)d_in[3];
    const float* kr   = (const float*)d_in[4];
    const float* br   = (const float*)d_in[5];
    const float* wo   = (const float*)d_in[6];
    const float* bo   = (const float*)d_in[7];
    float* y = (float*)d_out;

    char* ws = (char*)d_ws;
    size_t off = 0;
    unsigned short* Wp    = (unsigned short*)(ws + off); off += (size_t)4096 * KTOT * 2;        // 9,437,184
    float*          biasp = (float*)(ws + off);          off += (size_t)4096 * 4;               // 16,384
    unsigned short* Wob   = (unsigned short*)(ws + off); off += (size_t)OUT_ * H_ * 2;          // 131,072
    unsigned short* Ubf   = (unsigned short*)(ws + off); off += (size_t)T_ * B_ * IN_ * 2;      // 16,777,216
    unsigned short* Hall  = (unsigned short*)(ws + off); off += (size_t)(T_ + 1) * B_ * H_ * 2; // 134,479,872
    int*            Flag  = (int*)(ws + off);            off += (size_t)(T_ + 1) * GB * 64 * 4; // 525,312
    if (off > ws_size) return;   // workspace too small: deterministic visible failure

    // Sentinel-fill Hall (0xFFFF bf16 -NaN, unreachable as h) + clear flags.
    hipMemsetAsync(Hall, 0xFF, (size_t)(T_ + 1) * B_ * H_ * 2, stream);
    hipMemsetAsync(Flag, 0, (size_t)(T_ + 1) * GB * 64 * 4, stream);
    hipLaunchKernelGGL(pack_weights, dim3(4096),  dim3(256), 0, stream, kfiz, kr, bfiz, br, Wp, biasp);
    hipLaunchKernelGGL(pack_u,       dim3(32768), dim3(256), 0, stream, u, Ubf);
    hipLaunchKernelGGL(pack_wout,    dim3(64),    dim3(256), 0, stream, wo, Wob);

    void* args[] = { (void*)&x0, (void*)&Wp, (void*)&biasp, (void*)&Ubf, (void*)&Hall, (void*)&Flag };
    hipLaunchCooperativeKernel((void*)lstm_scan, dim3(GB * GH), dim3(512), args, 0, stream);

    hipLaunchKernelGGL(out_gemm, dim3((T_ * B_) / 64), dim3(256), 0, stream, Hall, Wob, bo, y);
}

// Round 10
// 2158.551 us; speedup vs baseline: 1.4092x; 1.3532x over previous
//
#include <hip/hip_runtime.h>
#include <hip/hip_bf16.h>

// Problem constants
#define B_    128
#define T_    512
#define IN_   128
#define H_    1024
#define OUT_  64
#define KTOT  1152          // IN_ + H_
#define GH    64            // hidden groups (16 units, 64 gate cols each)
#define GB    4             // batch groups (32 rows each)
// Blocked Hall layout: [t][gh(64)][b(128)][16] ushort.
// t-slab stride = 131072 ushorts (256KB); gh block = 2048 ushorts (4KB).
#define HSLAB 131072
#define HBLK  2048

typedef short bf16x8 __attribute__((ext_vector_type(8)));
typedef float f32x4  __attribute__((ext_vector_type(4)));

#define MFMA(a,b,c) __builtin_amdgcn_mfma_f32_16x16x32_bf16((a),(b),(c),0,0,0)

__device__ __forceinline__ unsigned short f2bf(float x) {
    unsigned int xi = __float_as_uint(x);
    unsigned int r  = (xi + 0x7fffu + ((xi >> 16) & 1u)) >> 16;
    return (unsigned short)r;
}

// ---------------------------------------------------------------------------
// Pack combined recurrent weights: Wp[c][k] bf16, c = gh*64 + unit_local*4 + gate
// gate 0,1,2 = f,i,z (kernel_fiz col gate*H + j); gate 3 = r (kernel_r col j)
// ---------------------------------------------------------------------------
__global__ void pack_weights(const float* __restrict__ kfiz, const float* __restrict__ kr,
                             const float* __restrict__ bfiz, const float* __restrict__ br,
                             unsigned short* __restrict__ Wp, float* __restrict__ biasp)
{
    const int c    = blockIdx.x;            // 0..4095
    const int gh   = c >> 6, nl = c & 63;
    const int j    = gh * 16 + (nl >> 2);
    const int gate = nl & 3;
    for (int k = threadIdx.x; k < KTOT; k += 256) {
        float v = (gate < 3) ? kfiz[(size_t)k * 3072 + gate * 1024 + j]
                             : kr[(size_t)k * 1024 + j];
        Wp[(size_t)c * KTOT + k] = f2bf(v);
    }
    if (threadIdx.x == 0)
        biasp[c] = (gate < 3) ? bfiz[gate * 1024 + j] : br[j];
}

// u (B,T,IN) fp32 -> Ubf (T,B,IN) bf16
__global__ void pack_u(const float* __restrict__ u, unsigned short* __restrict__ Ubf)
{
    size_t i = (size_t)blockIdx.x * 256 + threadIdx.x;   // < 8388608
    int t = (int)(i >> 14);
    int rem = (int)(i & 16383);
    int b = rem >> 7, k = rem & 127;
    Ubf[i] = f2bf(u[((size_t)b << 16) + ((size_t)t << 7) + k]);
}

// W_out (H,OUT) fp32 -> Wob[o][k] bf16
__global__ void pack_wout(const float* __restrict__ wo, unsigned short* __restrict__ Wob)
{
    const int o = blockIdx.x;               // 0..63
    for (int k = threadIdx.x; k < H_; k += 256)
        Wob[(size_t)o * H_ + k] = f2bf(wo[(size_t)k * OUT_ + o]);
}

// ---------------------------------------------------------------------------
// Persistent recurrent scan — round-4 proven core (1900us) + LDS SUBSET
// EARLY-RELEASE (B1 deleted; producer protocol byte-identical to round 4).
//  * wave0 polls the gb's 64 producer flags exactly as before (same LLC
//    traffic — round-6 lesson: never add pollers). Each ballot iteration it
//    compares against 4 subset masks and early-releases waves via LDS
//    rel[nj] = t+1 (monotonic counters; no reset race). Waves 1..7 spin on
//    their LDS word (same-address broadcast, zero global traffic) and start
//    their h-loads/MFMAs while the remaining producers straggle: per-wave
//    dependency drops from max-of-64 to max-of-18 (10 for nj=0), and the
//    wait overlaps the ~1000cy load+MFMA phase.
//  * Subset masks: wave nj touches h cols [nj*288-128, nj*288+160) ->
//    producers gh in [18nj-8, 18nj+10); nj=0: gh 0..9.
//  * Barrier-hazard audit: part[] writes (step t) occur after release(t),
//    which is after B2b(t-1) for all waves -> cannot race t-1's owner-reduce
//    reads. hT writes (t) occur after B2a(t), which requires wave0's arrival,
//    which is after wave0's hT(t-1) publish read. B2a/B2b unchanged.
//  * All spins bounded: a protocol failure degrades to a visible absmax
//    failure, never a hang.
// ---------------------------------------------------------------------------
__global__ void __launch_bounds__(512, 2)
lstm_scan(const float* __restrict__ x0,
          const unsigned short* __restrict__ Wp,
          const float* __restrict__ biasp,
          const unsigned short* __restrict__ Ubf,
          unsigned short* __restrict__ Hall,
          int* __restrict__ Flag)
{
    __shared__ float part[4 * 8 * 320];       // [nj][mi*4+tl][col*20 + row] 40 KB
    __shared__ unsigned short hT[32 * 16];    // 1 KB h-tile for coalesced publish
    __shared__ int rel[4];                    // per-subset release counters

    const int tid  = threadIdx.x;
    const int bid  = blockIdx.x;
    const int gb   = (bid & 7) >> 1;                 // XCD-pair -> one gb group
    const int gh   = ((bid & 1) << 5) | (bid >> 3);  // 0..63, unique per gb
    const int wave = tid >> 6;
    const int lane = tid & 63;
    const int mi   = wave & 1;
    const int nj   = wave >> 1;               // K-slice AND owner-tile index, 0..3
    const int quad = lane >> 4;
    const int l15  = lane & 15;
    const int g    = l15 & 3;                 // gate id of this lane's column

    // Weights: tile tl cols gh*64+tl*16+l15, K-slice nj chunks kk (9 x 32).
    f32x4 wregf[36];
    #pragma unroll
    for (int tl = 0; tl < 4; ++tl)
        #pragma unroll
        for (int kk = 0; kk < 9; ++kk)
            wregf[tl * 9 + kk] = *reinterpret_cast<const f32x4*>(
                Wp + (size_t)(gh * 64 + tl * 16 + l15) * KTOT + nj * 288 + kk * 32 + quad * 8);
    #pragma unroll
    for (int i = 0; i < 36; ++i)
        asm volatile("" : "+v"(wregf[i]));    // pin: no remat, keep in VGPRs

    const float bias = biasp[gh * 64 + nj * 16 + l15];   // owner-role bias

    const int rowBase = gb * 32 + mi * 16;
    const int j       = gh * 16 + nj * 4 + (l15 >> 2);   // owner-role unit col

    // c-state (fp32, replicated across the 4 gate lanes of each unit)
    float cst[4];
    #pragma unroll
    for (int r = 0; r < 4; ++r)
        cst[r] = x0[(size_t)(rowBase + quad * 4 + r) * 2048 + 1024 + j];

    if (tid < 4) rel[tid] = 0;                 // init release counters

    // h0 -> Hall[0] (blocked layout; WG's 1KB patch, contiguous full lines)
    {
        int m = tid >> 4, uu = tid & 15;      // 512 threads, 512 elems
        int b = gb * 32 + m;
        unsigned short hv = f2bf(x0[(size_t)b * 2048 + gh * 16 + uu]);
        __hip_atomic_store(&Hall[(size_t)gh * HBLK + (size_t)b * 16 + uu], hv,
                           __ATOMIC_RELAXED, __HIP_MEMORY_SCOPE_AGENT);
    }
    __syncthreads();                           // drains stores; rel[] visible
    if (tid == 0)
        __hip_atomic_store(&Flag[(size_t)gb * 64 + gh], 1,
                           __ATOMIC_RELAXED, __HIP_MEMORY_SCOPE_AGENT);

    const int aRow = rowBase + l15;            // A-frag row (batch index)
    const unsigned short* aU = Ubf + (size_t)aRow * IN_ + quad * 8;
    // Blocked consumer base: chunk kk (col c = nj*288-128+kk*32) lives in
    // block (nj*18-8+2*kk)+(quad>>1), byte-col (quad&1)*8 ushorts.
    const unsigned short* aH = Hall + (size_t)aRow * 16 + (quad >> 1) * HBLK + (quad & 1) * 8;
    const ptrdiff_t hBlk0 = (ptrdiff_t)(nj * 18 - 8) * HBLK;   // kk=0 block offset

    const int kk0 = (nj == 0) ? 4 : 0;         // post-poll chunk start

    for (int t = 0; t < T_; ++t) {
        f32x4 acc[4] = {{0.f,0.f,0.f,0.f},{0.f,0.f,0.f,0.f},
                        {0.f,0.f,0.f,0.f},{0.f,0.f,0.f,0.f}};

        // ---- pre-poll u-part (nj==0 waves own K-chunks 0..3 = u) ----
        if (nj == 0) {
            const unsigned short* au = aU + (size_t)t * (B_ * IN_);
            #pragma unroll
            for (int kk = 0; kk < 4; ++kk) {
                bf16x8 av = *reinterpret_cast<const bf16x8*>(au + kk * 32);
                #pragma unroll
                for (int tl = 0; tl < 4; ++tl)
                    acc[tl] = MFMA(av, __builtin_bit_cast(bf16x8, wregf[tl * 9 + kk]), acc[tl]);
            }
        }

        // ---- wave0: poll 64 flags (r4 traffic), early-release subsets ----
        if (wave == 0) {
            const int* fp = Flag + ((size_t)t * GB + gb) * 64 + lane;
            int relMask = 0;
            for (int gd = 0; gd < (1 << 16); ++gd) {
                int v = __hip_atomic_load(fp, __ATOMIC_RELAXED, __HIP_MEMORY_SCOPE_AGENT);
                unsigned long long b = __ballot(v != 0);
                if (lane == 0) {
                    if (!(relMask & 1) && (b & 0x3FFull) == 0x3FFull) {
                        __hip_atomic_store(&rel[0], t + 1, __ATOMIC_RELEASE, __HIP_MEMORY_SCOPE_WORKGROUP);
                        relMask |= 1;
                    }
                    if (!(relMask & 2) && (b & 0x0FFFFC00ull) == 0x0FFFFC00ull) {
                        __hip_atomic_store(&rel[1], t + 1, __ATOMIC_RELEASE, __HIP_MEMORY_SCOPE_WORKGROUP);
                        relMask |= 2;
                    }
                    if (!(relMask & 4) && (b & 0x00003FFFF0000000ull) == 0x00003FFFF0000000ull) {
                        __hip_atomic_store(&rel[2], t + 1, __ATOMIC_RELEASE, __HIP_MEMORY_SCOPE_WORKGROUP);
                        relMask |= 4;
                    }
                    if (!(relMask & 8) && (b & 0xFFFFC00000000000ull) == 0xFFFFC00000000000ull) {
                        __hip_atomic_store(&rel[3], t + 1, __ATOMIC_RELEASE, __HIP_MEMORY_SCOPE_WORKGROUP);
                        relMask |= 8;
                    }
                }
                if (b == ~0ull) break;
            }
        } else {
            // ---- waves 1..7: LDS spin on their subset (zero global traffic)
            for (int gd = 0; gd < (1 << 18); ++gd)
                if (__hip_atomic_load(&rel[nj], __ATOMIC_ACQUIRE, __HIP_MEMORY_SCOPE_WORKGROUP) >= t + 1)
                    break;
        }
        asm volatile("" ::: "memory");         // no h-load hoists above release

        // ---- h-part: this wave's K-slice (blocked layout, plain 512B runs) ----
        const ptrdiff_t hoff = (ptrdiff_t)t * HSLAB + hBlk0;
        bf16x8 a[9];
        #pragma unroll
        for (int kk = 0; kk < 9; ++kk)
            if (kk >= kk0)
                a[kk] = *reinterpret_cast<const bf16x8*>(aH + hoff + (ptrdiff_t)kk * (2 * HBLK));
        #pragma unroll
        for (int kk = 0; kk < 9; ++kk)
            if (kk >= kk0) {
                #pragma unroll
                for (int tl = 0; tl < 4; ++tl)
                    acc[tl] = MFMA(a[kk], __builtin_bit_cast(bf16x8, wregf[tl * 9 + kk]), acc[tl]);
            }

        // ---- write partials to LDS: part[nj][mi*4+tl][col l15][rows quad*4..] ----
        #pragma unroll
        for (int tl = 0; tl < 4; ++tl)
            *reinterpret_cast<f32x4*>(
                &part[(nj * 8 + mi * 4 + tl) * 320 + l15 * 20 + quad * 4]) = acc[tl];
        __syncthreads();                       // B2a

        // ---- owner reduce (this wave owns tile tl == nj for row-half mi) ----
        f32x4 s = {bias, bias, bias, bias};
        {
            const int rbase = (mi * 4 + nj) * 320 + l15 * 20 + quad * 4;
            #pragma unroll
            for (int njj = 0; njj < 4; ++njj)
                s += *reinterpret_cast<const f32x4*>(&part[njj * 2560 + rbase]);
        }

        // ---- epilogue: activations, cross-gate exchange, state update ----
        #pragma unroll
        for (int r = 0; r < 4; ++r) {
            float pre = s[r];
            float sg  = 1.0f / (1.0f + __expf((g == 3) ? -2.0f * pre : -pre));
            float act = (g == 3) ? 2.0f * sg - 1.0f : sg;
            float x1 = __shfl_xor(act, 1);
            float x2 = __shfl_xor(act, 2);
            float x3 = __shfl_xor(x1, 2);
            float fv = (g == 0) ? act : (g == 1) ? x1 : (g == 2) ? x2 : x3;
            int gi = g ^ 1;
            float iv = (gi == 0) ? act : (gi == 1) ? x1 : (gi == 2) ? x2 : x3;
            int gz = g ^ 2;
            float zv = (gz == 0) ? act : (gz == 1) ? x1 : (gz == 2) ? x2 : x3;
            int gr = g ^ 3;
            float rv = (gr == 0) ? act : (gr == 1) ? x1 : (gr == 2) ? x2 : x3;

            float cn = fv * cst[r] + iv * rv;
            cst[r] = cn;
            float th = 2.0f / (1.0f + __expf(-2.0f * cn)) - 1.0f;
            float hn = zv * th;
            if (g == 0)
                hT[(mi * 16 + quad * 4 + r) * 16 + nj * 4 + (l15 >> 2)] = f2bf(hn);
        }

        __syncthreads();                       // B2b: hT complete

        // ---- wave0: publish the WG's 1KB CONTIGUOUS patch, drain, flag ----
        if (wave == 0) {
            const unsigned long long* lp =
                reinterpret_cast<const unsigned long long*>(hT);
            unsigned long long lo = lp[lane], hi = lp[lane + 64];
            size_t base = (size_t)(t + 1) * HSLAB + (size_t)gh * HBLK
                        + (size_t)(gb * 32) * 16;
            __hip_atomic_store((unsigned long long*)&Hall[base + lane * 4],       lo,
                               __ATOMIC_RELAXED, __HIP_MEMORY_SCOPE_AGENT);
            __hip_atomic_store((unsigned long long*)&Hall[base + 256 + lane * 4], hi,
                               __ATOMIC_RELAXED, __HIP_MEMORY_SCOPE_AGENT);
            __builtin_amdgcn_s_waitcnt(0);     // drain: flag must mean "visible"
            asm volatile("" ::: "memory");
            if (lane == 0)
                __hip_atomic_store(&Flag[((size_t)(t + 1) * GB + gb) * 64 + gh], 1,
                                   __ATOMIC_RELAXED, __HIP_MEMORY_SCOPE_AGENT);
        }
    }
}

// ---------------------------------------------------------------------------
// y[b][t][o] = Hall[t+1][.][b][.] @ Wob[o][:] + bout[o]   (blocked Hall)
// ---------------------------------------------------------------------------
__global__ void __launch_bounds__(256, 2)
out_gemm(const unsigned short* __restrict__ Hall,
         const unsigned short* __restrict__ Wob,
         const float* __restrict__ bout,
         float* __restrict__ y)
{
    const int tid  = threadIdx.x, wave = tid >> 6, lane = tid & 63;
    const int quad = lane >> 4, l15 = lane & 15;
    const int R    = blockIdx.x * 64 + wave * 16;      // flat row t*128+b

    f32x4 acc[4];
    #pragma unroll
    for (int nt = 0; nt < 4; ++nt) {
        float bb = bout[nt * 16 + l15];
        acc[nt] = {bb, bb, bb, bb};
    }
    const int fr = R + l15;                    // flat row; same t across the wave
    const unsigned short* ap = Hall + ((size_t)(fr >> 7) + 1) * HSLAB
                             + (size_t)(fr & 127) * 16
                             + (quad >> 1) * HBLK + (quad & 1) * 8;
    #pragma unroll 4
    for (int kk = 0; kk < 32; ++kk) {          // k-chunk kk covers blocks 2kk,2kk+1
        bf16x8 av = *reinterpret_cast<const bf16x8*>(ap + (size_t)kk * (2 * HBLK));
        #pragma unroll
        for (int nt = 0; nt < 4; ++nt) {
            bf16x8 bv = *reinterpret_cast<const bf16x8*>(
                Wob + (size_t)(nt * 16 + l15) * H_ + kk * 32 + quad * 8);
            acc[nt] = MFMA(av, bv, acc[nt]);
        }
    }
    #pragma unroll
    for (int nt = 0; nt < 4; ++nt)
        #pragma unroll
        for (int r = 0; r < 4; ++r) {
            int row = R + quad * 4 + r;
            int b = row & 127, t = row >> 7;
            y[((size_t)b << 15) + ((size_t)t << 6) + nt * 16 + l15] = acc[nt][r];
        }
}

// ---------------------------------------------------------------------------
extern "C" void kernel_launch(void* const* d_in, const int* in_sizes, int n_in,
                              void* d_out, int out_size, void* d_ws, size_t ws_size,
                              hipStream_t stream)
{
    const float* u    = (const float*)d_in[0];
    const float* x0   = (const float*)d_in[1];
    const float* kfiz = (const float*)d_in[2];
    const float* bfiz = (const float*)d_in[3];
    const float* kr   = (const float*)d_in[4];
    const float* br   = (const float*)d_in[5];
    const float* wo   = (const float*)d_in[6];
    const float* bo   = (const float*)d_in[7];
    float* y = (float*)d_out;

    char* ws = (char*)d_ws;
    size_t off = 0;
    unsigned short* Wp    = (unsigned short*)(ws + off); off += (size_t)4096 * KTOT * 2;        // 9,437,184
    float*          biasp = (float*)(ws + off);          off += (size_t)4096 * 4;               // 16,384
    unsigned short* Wob   = (unsigned short*)(ws + off); off += (size_t)OUT_ * H_ * 2;          // 131,072
    unsigned short* Ubf   = (unsigned short*)(ws + off); off += (size_t)T_ * B_ * IN_ * 2;      // 16,777,216
    unsigned short* Hall  = (unsigned short*)(ws + off); off += (size_t)(T_ + 1) * B_ * H_ * 2; // 134,479,872
    int*            Flag  = (int*)(ws + off);            off += (size_t)(T_ + 1) * GB * 64 * 4; // 525,312
    if (off > ws_size) return;   // workspace too small: deterministic visible failure

    hipMemsetAsync(Flag, 0, (size_t)(T_ + 1) * GB * 64 * 4, stream);
    hipLaunchKernelGGL(pack_weights, dim3(4096),  dim3(256), 0, stream, kfiz, kr, bfiz, br, Wp, biasp);
    hipLaunchKernelGGL(pack_u,       dim3(32768), dim3(256), 0, stream, u, Ubf);
    hipLaunchKernelGGL(pack_wout,    dim3(64),    dim3(256), 0, stream, wo, Wob);

    void* args[] = { (void*)&x0, (void*)&Wp, (void*)&biasp, (void*)&Ubf, (void*)&Hall, (void*)&Flag };
    hipLaunchCooperativeKernel((void*)lstm_scan, dim3(GB * GH), dim3(512), args, 0, stream);

    hipLaunchKernelGGL(out_gemm, dim3((T_ * B_) / 64), dim3(256), 0, stream, Hall, Wob, bo, y);
}